// Round 3
// baseline (325.395 us; speedup 1.0000x reference)
//
#include <hip/hip_runtime.h>

// out[b,s,d] = X[b,s,d] * W[r][0] + Y[b,s,d] * W[r][1],  r = reward[b,s] in {0,1}
// B=4, S=4096, D=2048 (f32). Memory-bound: 402 MB demand traffic -> ~64us floor.
//
// Round 3: same as round 2 but with a native clang vector type so
// __builtin_nontemporal_store compiles (HIP float4 is a class, rejected).
//   (a) unroll x4 grid-stride -> 8 outstanding 16B loads/wave
//   (b) nt stores keep the output stream from evicting LLC-warm X/Y

#define LOG2_F4ROW  9   // 2048 floats/row = 512 float4/row

typedef float f32x4 __attribute__((ext_vector_type(4)));

__global__ __launch_bounds__(256) void
mla_kernel(const float* __restrict__ X,
           const float* __restrict__ Y,
           const int*   __restrict__ reward,
           const float* __restrict__ W,
           float*       __restrict__ out,
           long long n4)
{
    const float w00 = W[0], w01 = W[1];  // row 0: [alpha0, 1-alpha0]
    const float w10 = W[2], w11 = W[3];  // row 1: [alpha1, 1-alpha1]

    const long long stride = (long long)gridDim.x * blockDim.x;
    long long i = (long long)blockIdx.x * blockDim.x + threadIdx.x;

    const f32x4* __restrict__ X4 = reinterpret_cast<const f32x4*>(X);
    const f32x4* __restrict__ Y4 = reinterpret_cast<const f32x4*>(Y);
    f32x4*       __restrict__ O4 = reinterpret_cast<f32x4*>(out);

    // Main loop: 4 grid-stride slots per iteration -> 8 loads in flight.
    for (; i + 3 * stride < n4; i += 4 * stride) {
        const long long j0 = i, j1 = i + stride, j2 = i + 2 * stride, j3 = i + 3 * stride;

        // Issue all global loads before any use.
        const f32x4 x0 = X4[j0], x1 = X4[j1], x2 = X4[j2], x3 = X4[j3];
        const f32x4 y0 = Y4[j0], y1 = Y4[j1], y2 = Y4[j2], y3 = Y4[j3];
        const int r0 = reward[j0 >> LOG2_F4ROW];   // wave-uniform, L1-resident
        const int r1 = reward[j1 >> LOG2_F4ROW];
        const int r2 = reward[j2 >> LOG2_F4ROW];
        const int r3 = reward[j3 >> LOG2_F4ROW];

        const float a0 = r0 ? w10 : w00, b0 = r0 ? w11 : w01;
        const float a1 = r1 ? w10 : w00, b1 = r1 ? w11 : w01;
        const float a2 = r2 ? w10 : w00, b2 = r2 ? w11 : w01;
        const float a3 = r3 ? w10 : w00, b3 = r3 ? w11 : w01;

        f32x4 o0, o1, o2, o3;
        o0 = x0 * a0 + y0 * b0;
        o1 = x1 * a1 + y1 * b1;
        o2 = x2 * a2 + y2 * b2;
        o3 = x3 * a3 + y3 * b3;

        __builtin_nontemporal_store(o0, &O4[j0]);
        __builtin_nontemporal_store(o1, &O4[j1]);
        __builtin_nontemporal_store(o2, &O4[j2]);
        __builtin_nontemporal_store(o3, &O4[j3]);
    }

    // Tail (never taken for the benchmark shape: 8.4M float4 / 524288 = 16 exact).
    for (; i < n4; i += stride) {
        const int r = reward[i >> LOG2_F4ROW];
        const float a = r ? w10 : w00, b = r ? w11 : w01;
        const f32x4 x = X4[i], y = Y4[i];
        const f32x4 o = x * a + y * b;
        __builtin_nontemporal_store(o, &O4[i]);
    }
}

extern "C" void kernel_launch(void* const* d_in, const int* in_sizes, int n_in,
                              void* d_out, int out_size, void* d_ws, size_t ws_size,
                              hipStream_t stream)
{
    // setup_inputs() order: X, Y, reward, W
    const float* X      = (const float*)d_in[0];
    const float* Y      = (const float*)d_in[1];
    const int*   reward = (const int*)  d_in[2];
    const float* W      = (const float*)d_in[3];
    float*       out    = (float*)d_out;

    const long long n  = (long long)out_size;      // B*S*D = 33,554,432
    const long long n4 = n >> 2;                   // 8,388,608 float4

    const int block = 256;
    const int grid  = 2048;                        // 8 blocks/CU; 16 f4/thread -> 4 unrolled iters

    mla_kernel<<<grid, block, 0, stream>>>(X, Y, reward, W, out, n4);
}

// Round 4
// 299.684 us; speedup vs baseline: 1.0858x; 1.0858x over previous
//
#include <hip/hip_runtime.h>

// out[b,s,d] = X[b,s,d] * W[r][0] + Y[b,s,d] * W[r][1],  r = reward[b,s] in {0,1}
// B=4, S=4096, D=2048 (f32). Memory-bound.
//
// Round 4: isolate the round-1 suspect (VGPR=12 forcing per-iteration
// store-completion serialization) by removing the loop: 1 float4 per thread,
// 32768 blocks x 256 threads. Normal (writeback) stores — poison leaves d_out
// dirty-resident in LLC, so writeback hits are cheap; nt regressed (round 3).

#define LOG2_F4ROW  9   // 2048 floats/row = 512 float4/row

typedef float f32x4 __attribute__((ext_vector_type(4)));

__global__ __launch_bounds__(256) void
mla_kernel(const float* __restrict__ X,
           const float* __restrict__ Y,
           const int*   __restrict__ reward,
           const float* __restrict__ W,
           float*       __restrict__ out)
{
    const long long i = (long long)blockIdx.x * blockDim.x + threadIdx.x;

    const f32x4* __restrict__ X4 = reinterpret_cast<const f32x4*>(X);
    const f32x4* __restrict__ Y4 = reinterpret_cast<const f32x4*>(Y);
    f32x4*       __restrict__ O4 = reinterpret_cast<f32x4*>(out);

    // Issue all three loads up front (independent).
    const f32x4 x = X4[i];
    const f32x4 y = Y4[i];
    const int   r = reward[i >> LOG2_F4ROW];   // wave-uniform (512 f4/row), L1-hit

    // W is 4 floats, L1-resident; select per-thread (v_cndmask, no divergence).
    const float a = r ? W[2] : W[0];
    const float b = r ? W[3] : W[1];

    O4[i] = x * a + y * b;
}

extern "C" void kernel_launch(void* const* d_in, const int* in_sizes, int n_in,
                              void* d_out, int out_size, void* d_ws, size_t ws_size,
                              hipStream_t stream)
{
    // setup_inputs() order: X, Y, reward, W
    const float* X      = (const float*)d_in[0];
    const float* Y      = (const float*)d_in[1];
    const int*   reward = (const int*)  d_in[2];
    const float* W      = (const float*)d_in[3];
    float*       out    = (float*)d_out;

    const long long n  = (long long)out_size;  // 33,554,432
    const long long n4 = n >> 2;               // 8,388,608 float4 (exact multiple of 256)

    const int block = 256;
    const int grid  = (int)(n4 / block);       // 32768 blocks, 1 float4/thread

    mla_kernel<<<grid, block, 0, stream>>>(X, Y, reward, W, out);
}